// Round 1
// baseline (247.100 us; speedup 1.0000x reference)
//
#include <hip/hip_runtime.h>

#define NXD 4096
#define NYD 4096

__global__ __launch_bounds__(256) void DiffReactParamPDE_85478439125433_kernel(
    const float* __restrict__ state,
    const float* __restrict__ bc,
    const float* __restrict__ a_org,
    const float* __restrict__ b_org,
    const float* __restrict__ k_org,
    float* __restrict__ out)
{
    const float inv_dx2 = 100.0f;  // 1/(0.1*0.1)

    // sigmoid(x) * 0.01 — uniform scalars, computed per thread (cached loads)
    const float a = 0.01f / (1.0f + expf(-a_org[0]));
    const float b = 0.01f / (1.0f + expf(-b_org[0]));
    const float k = 0.01f / (1.0f + expf(-k_org[0]));

    // bc layout (1,2,4): [U: left,right,top,bottom | V: left,right,top,bottom]
    const float uL = bc[0], uR = bc[1], uT = bc[2], uB = bc[3];
    const float vL = bc[4], vR = bc[5], vT = bc[6], vB = bc[7];

    const int j0 = (blockIdx.x * blockDim.x + threadIdx.x) * 4;  // column of first elem
    const int i  = blockIdx.y;                                    // row
    if (j0 >= NYD || i >= NXD) return;

    const float* __restrict__ U = state;
    const float* __restrict__ V = state + (size_t)NXD * NYD;
    float* __restrict__ dU = out;
    float* __restrict__ dV = out + (size_t)NXD * NYD;

    const size_t base = (size_t)i * NYD + j0;

    // center rows
    const float4 uc = *(const float4*)(U + base);
    const float4 vc = *(const float4*)(V + base);

    // vertical neighbors (row i-1 = "top" pad at i==0, row i+1 = "bottom" pad at i==NX-1)
    float4 uu, ud, vu, vd;
    if (i > 0) {
        uu = *(const float4*)(U + base - NYD);
        vu = *(const float4*)(V + base - NYD);
    } else {
        uu = make_float4(uT, uT, uT, uT);
        vu = make_float4(vT, vT, vT, vT);
    }
    if (i < NXD - 1) {
        ud = *(const float4*)(U + base + NYD);
        vd = *(const float4*)(V + base + NYD);
    } else {
        ud = make_float4(uB, uB, uB, uB);
        vd = make_float4(vB, vB, vB, vB);
    }

    // horizontal edge neighbors of the 4-vector
    const float ul = (j0 > 0)        ? U[base - 1] : uL;
    const float ur = (j0 + 4 < NYD)  ? U[base + 4] : uR;
    const float vl = (j0 > 0)        ? V[base - 1] : vL;
    const float vr = (j0 + 4 < NYD)  ? V[base + 4] : vR;

    // Laplacians: (up + down + left + right - 4*center) * inv_dx2
    float lu0 = (uu.x + ud.x + ul   + uc.y - 4.0f * uc.x) * inv_dx2;
    float lu1 = (uu.y + ud.y + uc.x + uc.z - 4.0f * uc.y) * inv_dx2;
    float lu2 = (uu.z + ud.z + uc.y + uc.w - 4.0f * uc.z) * inv_dx2;
    float lu3 = (uu.w + ud.w + uc.z + ur   - 4.0f * uc.w) * inv_dx2;

    float lv0 = (vu.x + vd.x + vl   + vc.y - 4.0f * vc.x) * inv_dx2;
    float lv1 = (vu.y + vd.y + vc.x + vc.z - 4.0f * vc.y) * inv_dx2;
    float lv2 = (vu.z + vd.z + vc.y + vc.w - 4.0f * vc.z) * inv_dx2;
    float lv3 = (vu.w + vd.w + vc.z + vr   - 4.0f * vc.w) * inv_dx2;

    // dUdt = a*lap_u + U - U^3 - V - k
    float4 du_out;
    du_out.x = a * lu0 + uc.x - uc.x * uc.x * uc.x - vc.x - k;
    du_out.y = a * lu1 + uc.y - uc.y * uc.y * uc.y - vc.y - k;
    du_out.z = a * lu2 + uc.z - uc.z * uc.z * uc.z - vc.z - k;
    du_out.w = a * lu3 + uc.w - uc.w * uc.w * uc.w - vc.w - k;

    // dVdt = b*lap_v + U - V
    float4 dv_out;
    dv_out.x = b * lv0 + uc.x - vc.x;
    dv_out.y = b * lv1 + uc.y - vc.y;
    dv_out.z = b * lv2 + uc.z - vc.z;
    dv_out.w = b * lv3 + uc.w - vc.w;

    *(float4*)(dU + base) = du_out;
    *(float4*)(dV + base) = dv_out;
}

extern "C" void kernel_launch(void* const* d_in, const int* in_sizes, int n_in,
                              void* d_out, int out_size, void* d_ws, size_t ws_size,
                              hipStream_t stream) {
    const float* state = (const float*)d_in[0];
    const float* bc    = (const float*)d_in[1];
    const float* a_org = (const float*)d_in[2];
    const float* b_org = (const float*)d_in[3];
    const float* k_org = (const float*)d_in[4];
    float* out = (float*)d_out;

    // 4096 cols / 4 per thread / 256 threads = 4 blocks in x; 4096 rows in y
    dim3 block(256, 1, 1);
    dim3 grid(NYD / (4 * 256), NXD, 1);
    DiffReactParamPDE_85478439125433_kernel<<<grid, block, 0, stream>>>(
        state, bc, a_org, b_org, k_org, out);
}